// Round 15
// baseline (990.806 us; speedup 1.0000x reference)
//
#include <hip/hip_runtime.h>
#include <hip/hip_bf16.h>
#include <math.h>

#define N_NODES 50000
#define E_EDGES 800000
#define D_DIM   128
#define H_HEADS 8
#define ETILES  4

typedef __attribute__((ext_vector_type(8))) short short8;
typedef __attribute__((ext_vector_type(4))) float f32x4;
typedef unsigned int   uint_t;
typedef unsigned short ushort_t;

static __device__ __forceinline__ float4 ldg4(const float* p) {
    return *reinterpret_cast<const float4*>(p);
}
// f32 -> bf16 bits, round-to-nearest-even
static __device__ __forceinline__ ushort_t f2bf(float x) {
    union { float f; uint_t u; } v; v.f = x;
    uint_t r = v.u + 0x7fffu + ((v.u >> 16) & 1u);
    return (ushort_t)(r >> 16);
}
static __device__ __forceinline__ float bf2f(ushort_t b) {
    union { uint_t u; float f; } v; v.u = ((uint_t)b) << 16;
    return v.f;
}
static __device__ __forceinline__ uint_t pk(float lo, float hi) {
    return (uint_t)f2bf(lo) | ((uint_t)f2bf(hi) << 16);
}

// ---------------- CSR build ----------------
__global__ void hist_kernel(const int* __restrict__ dst, int* __restrict__ hist) {
    int i = blockIdx.x * blockDim.x + threadIdx.x;
    if (i < E_EDGES) atomicAdd(&hist[dst[i]], 1);
}

__global__ __launch_bounds__(1024) void scan_kernel(const int* __restrict__ cnt,
                                                    int* __restrict__ start,
                                                    int* __restrict__ cursor) {
    __shared__ int sh[1024];
    const int t = threadIdx.x;
    const int CPT = (N_NODES + 1023) / 1024;
    int lo = t * CPT;
    int hi = lo + CPT; if (hi > N_NODES) hi = N_NODES; if (lo > N_NODES) lo = N_NODES;
    int s = 0;
    for (int i = lo; i < hi; i++) s += cnt[i];
    sh[t] = s;
    __syncthreads();
    for (int off = 1; off < 1024; off <<= 1) {
        int v = (t >= off) ? sh[t - off] : 0;
        __syncthreads();
        sh[t] += v;
        __syncthreads();
    }
    int run = sh[t] - s;
    for (int i = lo; i < hi; i++) {
        start[i]  = run;
        cursor[i] = run;
        run += cnt[i];
    }
    if (t == 1023) start[N_NODES] = sh[1023];
}

__global__ void scatter_kernel(const int* __restrict__ src, const int* __restrict__ dst,
                               int* __restrict__ cursor,
                               int* __restrict__ rank, int* __restrict__ srcs) {
    int i = blockIdx.x * blockDim.x + threadIdx.x;
    if (i < E_EDGES) {
        int p = atomicAdd(&cursor[dst[i]], 1);
        rank[i] = p;
        srcs[p] = src[i];
    }
}

// ---------------- weight prep: bf16, transposed [col][k], XOR-swizzled, 16KB tiles ----------------
__global__ __launch_bounds__(256) void prep_weights(const float* __restrict__ Wq,
                                                    const float* __restrict__ Wk,
                                                    const float* __restrict__ Wv,
                                                    const float* __restrict__ We,
                                                    const float* __restrict__ Wsdp,
                                                    const float* __restrict__ Wh1,
                                                    const float* __restrict__ Wh2,
                                                    ushort_t* __restrict__ prep) {
    const int b = blockIdx.x;
    const float* W; int ld, cb, kc;
    if (b < 6)       { W = (b < 2 ? Wq : (b < 4 ? Wk : Wv)); ld = 128; cb = 0; kc = b & 1; }
    else if (b < 8)  { W = We;   ld = 128; cb = 0;            kc = b - 6; }
    else if (b < 10) { W = Wsdp; ld = 128; cb = 0;            kc = b - 8; }
    else if (b < 14) { W = Wh1;  ld = 256; cb = (b - 10) >> 1; kc = (b - 10) & 1; }
    else             { W = Wh2;  ld = 128; cb = 0;            kc = b - 14; }
    char* tile = (char*)(prep + (size_t)b * 8192);
    for (int i = threadIdx.x; i < 8192; i += 256) {
        int col = i >> 6, kl = i & 63;
        int k = kc * 64 + kl;
        float v = W[(size_t)k * ld + cb * 128 + col];
        int byte = (col * 128 + kl * 2) ^ ((col & 7) << 4);
        *(ushort_t*)(tile + byte) = f2bf(v);
    }
}

// ---------------- We in MFMA-fragment-linear layout (32KB) ----------------
__global__ __launch_bounds__(256) void prep_we_frag(const float* __restrict__ We,
                                                    ushort_t* __restrict__ WeF) {
    int slot = blockIdx.x * 256 + threadIdx.x;
    if (slot < 2048) {
        int lane = slot & 63;
        int kc   = (slot >> 6) & 3;
        int cg   = slot >> 8;
        int col  = cg * 16 + (lane & 15);
        int kb   = kc * 32 + ((lane >> 4) << 3);
#pragma unroll
        for (int j = 0; j < 8; j++)
            WeF[slot * 8 + j] = f2bf(We[(size_t)(kb + j) * 128 + col]);
    }
}

// ---------------- bf16 MFMA GEMM ----------------
// ROWS rows/block, 256 threads = 4 waves (2x2).
// OBF: bf16 out. ABF: bf16 A. RESMODE: 0=f32 resid, 1=bf16 resid, 2=f32 resid w/ scale-shift.
// SADD: per-col sum/sumsq accumulation. ASS: apply scale-shift to A (f32 path) during staging.
template<int ROWS, int OBF, int ABF, int RESMODE, int SADD, int ASS>
__global__ __launch_bounds__(256) void gemm_bf16(const void* __restrict__ Av,
                                                 int M, int K,
                                                 const ushort_t* __restrict__ Bt, int nkc,
                                                 const float* __restrict__ bias,
                                                 const void* __restrict__ residv,
                                                 void* __restrict__ Cv, int ldc,
                                                 size_t cbStride, int doRelu,
                                                 float* __restrict__ sums,
                                                 const float* __restrict__ ss) {
    constexpr int MI  = ROWS / 32;
    constexpr int TPR = 256 / ROWS;
    constexpr int KPT = 64 / TPR;
    __shared__ __align__(16) unsigned char As[ROWS * 128];
    __shared__ __align__(16) unsigned char Bs[16384];
    __shared__ float csum[128], csq[128];
    const int tid  = threadIdx.x;
    const int lane = tid & 63;
    const int wid  = tid >> 6;
    const int wr   = wid >> 1;
    const int wc   = wid & 1;
    const int cb   = blockIdx.y;
    const int row0 = blockIdx.x * ROWS;

    if (SADD && tid < 128) { csum[tid] = 0.f; csq[tid] = 0.f; }

    f32x4 acc[MI][4];
#pragma unroll
    for (int i = 0; i < MI; i++)
#pragma unroll
        for (int j = 0; j < 4; j++) acc[i][j] = (f32x4){0.f, 0.f, 0.f, 0.f};

    for (int kc = 0; kc < nkc; kc++) {
        __syncthreads();
        {   // stage A chunk: ROWS rows x 64 k
            int row = tid / TPR;
            int kl0 = (tid % TPR) * KPT;
            int gr  = row0 + row;
            int s = (row & 7) << 4;
            if (ABF) {
                const ushort_t* A16 = (const ushort_t*)Av;
#pragma unroll
                for (int j = 0; j < KPT / 8; j++) {
                    uint4 w = make_uint4(0, 0, 0, 0);
                    if (gr < M) w = *(const uint4*)(&A16[(size_t)gr * K + kc * 64 + kl0 + 8 * j]);
                    int byte = (row * 128 + (kl0 + 8 * j) * 2) ^ s;
                    *(uint4*)(As + byte) = w;
                }
            } else {
                const float* A = (const float*)Av;
                float4 v4[KPT / 4];
                if (gr < M) {
                    const float* ap = &A[(size_t)gr * K + kc * 64 + kl0];
#pragma unroll
                    for (int j = 0; j < KPT / 4; j++) v4[j] = ldg4(ap + 4 * j);
                } else {
#pragma unroll
                    for (int j = 0; j < KPT / 4; j++) v4[j] = make_float4(0.f, 0.f, 0.f, 0.f);
                }
                if (ASS) {
#pragma unroll
                    for (int j = 0; j < KPT / 4; j++) {
                        int kk = kc * 64 + kl0 + 4 * j;
                        v4[j].x = v4[j].x * ss[kk + 0] + ss[128 + kk + 0];
                        v4[j].y = v4[j].y * ss[kk + 1] + ss[128 + kk + 1];
                        v4[j].z = v4[j].z * ss[kk + 2] + ss[128 + kk + 2];
                        v4[j].w = v4[j].w * ss[kk + 3] + ss[128 + kk + 3];
                    }
                }
#pragma unroll
                for (int j = 0; j < KPT / 8; j++) {
                    uint4 w;
                    w.x = pk(v4[2 * j].x, v4[2 * j].y);
                    w.y = pk(v4[2 * j].z, v4[2 * j].w);
                    w.z = pk(v4[2 * j + 1].x, v4[2 * j + 1].y);
                    w.w = pk(v4[2 * j + 1].z, v4[2 * j + 1].w);
                    int byte = (row * 128 + (kl0 + 8 * j) * 2) ^ s;
                    *(uint4*)(As + byte) = w;
                }
            }
        }
        {   // stage B chunk: linear 16KB copy of prepped tile
            const uint4* gB = (const uint4*)(Bt + (size_t)(cb * nkc + kc) * 8192);
#pragma unroll
            for (int j = 0; j < 4; j++) {
                int idx = j * 256 + tid;
                ((uint4*)Bs)[idx] = gB[idx];
            }
        }
        __syncthreads();
#pragma unroll
        for (int k0 = 0; k0 < 64; k0 += 32) {
            short8 a[MI], b[4];
#pragma unroll
            for (int mi = 0; mi < MI; mi++) {
                int row = wr * (ROWS / 2) + mi * 16 + (lane & 15);
                int byte = (row * 128 + k0 * 2 + (lane >> 4) * 16) ^ ((row & 7) << 4);
                a[mi] = *(const short8*)(As + byte);
            }
#pragma unroll
            for (int ni = 0; ni < 4; ni++) {
                int col = wc * 64 + ni * 16 + (lane & 15);
                int byte = (col * 128 + k0 * 2 + (lane >> 4) * 16) ^ ((col & 7) << 4);
                b[ni] = *(const short8*)(Bs + byte);
            }
#pragma unroll
            for (int mi = 0; mi < MI; mi++)
#pragma unroll
                for (int ni = 0; ni < 4; ni++)
                    acc[mi][ni] = __builtin_amdgcn_mfma_f32_16x16x32_bf16(a[mi], b[ni], acc[mi][ni], 0, 0, 0);
        }
    }

    float colS[4] = {0.f, 0.f, 0.f, 0.f};
    float colQ[4] = {0.f, 0.f, 0.f, 0.f};
#pragma unroll
    for (int mi = 0; mi < MI; mi++) {
#pragma unroll
        for (int r = 0; r < 4; r++) {
            int row = row0 + wr * (ROWS / 2) + mi * 16 + ((lane >> 4) << 2) + r;
            if (row < M) {
#pragma unroll
                for (int ni = 0; ni < 4; ni++) {
                    int col = wc * 64 + ni * 16 + (lane & 15);
                    float v = acc[mi][ni][r];
                    if (bias) v += bias[cb * 128 + col];
                    if (doRelu) v = fmaxf(v, 0.f);
                    if (residv) {
                        if (RESMODE == 1) {
                            v += bf2f(((const ushort_t*)residv)[(size_t)row * ldc + col]);
                        } else if (RESMODE == 2) {
                            float rr = ((const float*)residv)[(size_t)row * ldc + col];
                            v += rr * ss[col] + ss[128 + col];
                        } else {
                            v += ((const float*)residv)[(size_t)row * ldc + col];
                        }
                    }
                    if (SADD) { colS[ni] += v; colQ[ni] += v * v; }
                    if (OBF) ((ushort_t*)Cv)[cb * cbStride + (size_t)row * ldc + col] = f2bf(v);
                    else     ((float*)Cv)[cb * cbStride + (size_t)row * ldc + col] = v;
                }
            }
        }
    }
    if (SADD) {
#pragma unroll
        for (int ni = 0; ni < 4; ni++) {
            int col = wc * 64 + ni * 16 + (lane & 15);
            atomicAdd(&csum[col], colS[ni]);
            atomicAdd(&csq[col],  colQ[ni]);
        }
        __syncthreads();
        if (tid < 128) {
            atomicAdd(&sums[tid],       csum[tid]);
            atomicAdd(&sums[128 + tid], csq[tid]);
        }
    }
}

// ---------------- fused edge kernel: round-9 body looped over ETILES tiles/block ----------------
// 512 threads = 8 waves (2 row-groups x 4 head-pair groups); 64 edges/tile; f32 32B S stores.
// NOTHING carried in registers across barriers/iterations (spill law).
__global__ __launch_bounds__(512, 8) void edge_mfma(const float* __restrict__ e,
                                                    const int* __restrict__ src,
                                                    const int* __restrict__ dst,
                                                    const ushort_t* __restrict__ Qm,
                                                    const ushort_t* __restrict__ Km,
                                                    const ushort_t* __restrict__ WeF,
                                                    const int* __restrict__ rank,
                                                    float* __restrict__ S,
                                                    float* __restrict__ out_e) {
    __shared__ __align__(16) unsigned char Asm[16384];  // 2 chunks x [64 rows][64 k] bf16 swizzled
    __shared__ float sm[64][8];                          // [edge-in-tile][head]
    const int tid  = threadIdx.x;
    const int lane = tid & 63;
    const int wid  = tid >> 6;
    const int wr   = wid >> 2;       // 0..1 : rows wr*32
    const int wc   = wid & 3;        // 0..3 : heads 2wc, 2wc+1
    const int base = blockIdx.x * (64 * ETILES);

#pragma unroll 1
    for (int t = 0; t < ETILES; t++) {
        const int e0 = base + t * 64;

        {   // stage e tile (f32 -> bf16 LDS) + f32 pass-through copy
            int row = tid >> 3;
            int c0  = (tid & 7) * 16;
            const float* ep = &e[(size_t)(e0 + row) * 128 + c0];
            float*       op = &out_e[(size_t)(e0 + row) * 128 + c0];
            float4 v4[4];
#pragma unroll
            for (int j = 0; j < 4; j++) v4[j] = ldg4(ep + 4 * j);
#pragma unroll
            for (int j = 0; j < 4; j++) *(float4*)(op + 4 * j) = v4[j];
            int chunk = c0 >> 6;
            int klb   = (c0 & 63) * 2;
            int s     = (row & 7) << 4;
            uint4 w0, w1;
            w0.x = pk(v4[0].x, v4[0].y); w0.y = pk(v4[0].z, v4[0].w);
            w0.z = pk(v4[1].x, v4[1].y); w0.w = pk(v4[1].z, v4[1].w);
            w1.x = pk(v4[2].x, v4[2].y); w1.y = pk(v4[2].z, v4[2].w);
            w1.z = pk(v4[3].x, v4[3].y); w1.w = pk(v4[3].z, v4[3].w);
            *(uint4*)(Asm + chunk * 8192 + ((row * 128 + klb) ^ s))      = w0;
            *(uint4*)(Asm + chunk * 8192 + ((row * 128 + klb + 16) ^ s)) = w1;
        }
        __syncthreads();

        f32x4 acc[2][2];
#pragma unroll
        for (int i = 0; i < 2; i++)
#pragma unroll
            for (int j = 0; j < 2; j++) acc[i][j] = (f32x4){0.f, 0.f, 0.f, 0.f};

#pragma unroll
        for (int k0 = 0; k0 < 128; k0 += 32) {
            int chunk = k0 >> 6;
            int klb   = (k0 & 63) * 2;
            int kc    = k0 >> 5;
            short8 a[2];
#pragma unroll
            for (int mi = 0; mi < 2; mi++) {
                int arow = wr * 32 + mi * 16 + (lane & 15);
                int byte = chunk * 8192 + ((arow * 128 + klb + (lane >> 4) * 16) ^ ((arow & 7) << 4));
                a[mi] = *(const short8*)(Asm + byte);
            }
#pragma unroll
            for (int ni = 0; ni < 2; ni++) {
                int cg = wc * 2 + ni;
                short8 b = *(const short8*)(WeF + ((size_t)((cg * 4 + kc) * 64 + lane)) * 8);
#pragma unroll
                for (int mi = 0; mi < 2; mi++)
                    acc[mi][ni] = __builtin_amdgcn_mfma_f32_16x16x32_bf16(a[mi], b, acc[mi][ni], 0, 0, 0);
            }
        }

        // epilogue: gather bf16 K[src]*Q[dst], 16-lane reduce, exp -> LDS
#pragma unroll
        for (int mi = 0; mi < 2; mi++) {
            int rows[4], sidx[4], didx[4];
#pragma unroll
            for (int r = 0; r < 4; r++) {
                rows[r] = e0 + wr * 32 + mi * 16 + ((lane >> 4) << 2) + r;
                sidx[r] = src[rows[r]];
                didx[r] = dst[rows[r]];
            }
#pragma unroll
            for (int ni = 0; ni < 2; ni++) {
                int head = wc * 2 + ni;
                int col  = head * 16 + (lane & 15);
                float pv[4];
#pragma unroll
                for (int r = 0; r < 4; r++) {
                    float kv = bf2f(Km[(size_t)sidx[r] * 128 + col]);
                    float qv = bf2f(Qm[(size_t)didx[r] * 128 + col]);
                    pv[r] = acc[mi][ni][r] * kv * qv;
                }
#pragma unroll
                for (int off = 1; off < 16; off <<= 1)
#pragma unroll
                    for (int r = 0; r < 4; r++) pv[r] += __shfl_xor(pv[r], off, 64);
                if ((lane & 15) == 0) {
#pragma unroll
                    for (int r = 0; r < 4; r++) {
                        float v = fminf(fmaxf(0.25f * pv[r], -5.f), 5.f);
                        sm[rows[r] - e0][head] = __expf(v);
                    }
                }
            }
        }
        __syncthreads();
        // sorted, contiguous 32B f32 store per edge (sector-aligned, no RMW)
        if (tid < 64) {
            int rk = rank[e0 + tid];
            float4 a0 = *(const float4*)&sm[tid][0];
            float4 a1 = *(const float4*)&sm[tid][4];
            *(float4*)&S[(size_t)rk * 8]     = a0;
            *(float4*)&S[(size_t)rk * 8 + 4] = a1;
        }
    }
}

// ---------------- aggregation: wave-per-node, f32 S + bf16 V, bf16 output ----------------
__global__ __launch_bounds__(256) void agg_kernel(const uint_t* __restrict__ Vu,
                                                  const float* __restrict__ S,
                                                  const int* __restrict__ start,
                                                  const int* __restrict__ srcs,
                                                  uint_t* __restrict__ HAu) {
    const int lane = threadIdx.x & 63;
    const int n = blockIdx.x * 4 + (threadIdx.x >> 6);
    if (n >= N_NODES) return;
    const int s0 = start[n];
    const int s1 = start[n + 1];
    const int h  = lane >> 3;
    float a0 = 0.f, a1 = 0.f, z = 0.f;
    int i = s0;
    for (; i + 4 <= s1; i += 4) {
        int m0 = srcs[i], m1 = srcs[i + 1], m2 = srcs[i + 2], m3 = srcs[i + 3];
        float t0 = S[(size_t)i * 8 + h];
        float t1 = S[(size_t)(i + 1) * 8 + h];
        float t2 = S[(size_t)(i + 2) * 8 + h];
        float t3 = S[(size_t)(i + 3) * 8 + h];
        uint_t v0 = Vu[(size_t)m0 * 64 + lane];
        uint_t v1 = Vu[(size_t)m1 * 64 + lane];
        uint_t v2 = Vu[(size_t)m2 * 64 + lane];
        uint_t v3 = Vu[(size_t)m3 * 64 + lane];
        a0 = fmaf(t0, bf2f((ushort_t)v0), a0); a1 = fmaf(t0, bf2f((ushort_t)(v0 >> 16)), a1);
        a0 = fmaf(t1, bf2f((ushort_t)v1), a0); a1 = fmaf(t1, bf2f((ushort_t)(v1 >> 16)), a1);
        a0 = fmaf(t2, bf2f((ushort_t)v2), a0); a1 = fmaf(t2, bf2f((ushort_t)(v2 >> 16)), a1);
        a0 = fmaf(t3, bf2f((ushort_t)v3), a0); a1 = fmaf(t3, bf2f((ushort_t)(v3 >> 16)), a1);
        z += t0 + t1 + t2 + t3;
    }
    for (; i < s1; i++) {
        int m = srcs[i];
        float t = S[(size_t)i * 8 + h];
        uint_t v = Vu[(size_t)m * 64 + lane];
        a0 = fmaf(t, bf2f((ushort_t)v), a0);
        a1 = fmaf(t, bf2f((ushort_t)(v >> 16)), a1);
        z += t;
    }
    float inv = 1.f / (z + 1e-6f);
    HAu[(size_t)n * 64 + lane] = pk(a0 * inv, a1 * inv);
}

// ---------------- batch norm: finalize sums -> scale/shift; apply y = x*scale+shift ----------------
__global__ void bn_finalize(const float* __restrict__ sums,
                            const float* __restrict__ gamma,
                            const float* __restrict__ beta,
                            float* __restrict__ ss) {
    int c = threadIdx.x;   // 128
    float mu  = sums[c] * (1.f / (float)N_NODES);
    float var = sums[128 + c] * (1.f / (float)N_NODES) - mu * mu;
    float scale = rsqrtf(var + 1e-5f) * gamma[c];
    ss[c]       = scale;
    ss[128 + c] = beta[c] - mu * scale;
}

__global__ __launch_bounds__(256) void bn_apply_f32(const float* __restrict__ X,
                                                    const float* __restrict__ ss,
                                                    float* __restrict__ Y) {
    const size_t total = (size_t)N_NODES * 128;
    const size_t step = (size_t)gridDim.x * blockDim.x * 4;
    for (size_t i = ((size_t)blockIdx.x * blockDim.x + threadIdx.x) * 4; i < total; i += step) {
        float4 x = ldg4(&X[i]);
        int c = (int)(i & 127);
        float4 y;
        y.x = x.x * ss[c + 0] + ss[128 + c + 0];
        y.y = x.y * ss[c + 1] + ss[128 + c + 1];
        y.z = x.z * ss[c + 2] + ss[128 + c + 2];
        y.w = x.w * ss[c + 3] + ss[128 + c + 3];
        *(float4*)(&Y[i]) = y;
    }
}

extern "C" void kernel_launch(void* const* d_in, const int* in_sizes, int n_in,
                              void* d_out, int out_size, void* d_ws, size_t ws_size,
                              hipStream_t stream) {
    (void)in_sizes; (void)n_in; (void)out_size; (void)ws_size;
    const int*   src   = (const int*)d_in[0];
    const int*   dst   = (const int*)d_in[1];
    const float* h     = (const float*)d_in[2];
    const float* e     = (const float*)d_in[3];
    const float* Wq    = (const float*)d_in[5];
    const float* Wk    = (const float*)d_in[6];
    const float* Wv    = (const float*)d_in[7];
    const float* We    = (const float*)d_in[8];
    const float* Wsdp  = (const float*)d_in[9];
    const float* bsdp  = (const float*)d_in[10];
    const float* Wh1   = (const float*)d_in[11];
    const float* bh1   = (const float*)d_in[12];
    const float* Wh2   = (const float*)d_in[13];
    const float* bh2   = (const float*)d_in[14];
    const float* gamma = (const float*)d_in[15];
    const float* beta  = (const float*)d_in[16];
    float* out = (float*)d_out;

    float* ws = (float*)d_ws;
    const size_t NM = (size_t)N_NODES * 128;   // 6.4M elements
    ushort_t* Q16  = (ushort_t*)ws;
    ushort_t* K16  = Q16 + NM;
    ushort_t* V16  = Q16 + 2 * NM;
    ushort_t* HA16 = (ushort_t*)(ws + 3 * NM / 2);
    float*    Kb   = ws + 2 * NM;
    float*    Sb   = ws + 3 * NM;   // f32 scores, sorted, [pos][8]
    float*    T1r  = ws + 4 * NM;
    ushort_t* T16  = (ushort_t*)T1r;
    float*    STATS = ws + 6 * NM;
    int* hist   = (int*)(STATS + 1024);
    int* startp = hist + N_NODES;
    int* cursor = startp + N_NODES + 1;
    ushort_t* prep = (ushort_t*)(((uintptr_t)(cursor + N_NODES) + 255) & ~(uintptr_t)255);
    ushort_t* WeF  = prep + (size_t)18 * 8192;

    int* rank = (int*)T1r;
    int* srcs = rank + E_EDGES;

    float* sums1 = STATS;
    float* ss1   = STATS + 256;
    float* sums2 = STATS + 512;
    float* ss2   = STATS + 768;

    prep_weights<<<18, 256, 0, stream>>>(Wq, Wk, Wv, We, Wsdp, Wh1, Wh2, prep);
    prep_we_frag<<<8, 256, 0, stream>>>(We, WeF);

    hipMemsetAsync(STATS, 0, (1024 + N_NODES) * sizeof(float), stream);

    hist_kernel<<<(E_EDGES + 255) / 256, 256, 0, stream>>>(dst, hist);
    scan_kernel<<<1, 1024, 0, stream>>>(hist, startp, cursor);
    scatter_kernel<<<(E_EDGES + 255) / 256, 256, 0, stream>>>(src, dst, cursor, rank, srcs);

    const int rt128 = (N_NODES + 127) / 128;   // 391
    const int rt64  = (N_NODES + 63) / 64;     // 782

    // q,k,v (bf16 out): cb = matrix (Q16,K16,V16)
    gemm_bf16<128, 1, 0, 0, 0, 0><<<dim3(rt128, 3), 256, 0, stream>>>(
        h, N_NODES, 128, prep, 2, nullptr, nullptr, Q16, 128, NM, 0, nullptr, nullptr);

    // fused edge scores (sorted f32 S, [pos][8]) + e pass-through copy — 4 tiles/block
    edge_mfma<<<E_EDGES / (64 * ETILES), 512, 0, stream>>>(e, src, dst, Q16, K16, WeF,
                                                           rank, Sb, out + NM);

    // aggregation -> h_attn bf16
    agg_kernel<<<(N_NODES + 3) / 4, 256, 0, stream>>>((const uint_t*)V16, Sb, startp, srcs,
                                                      (uint_t*)HA16);

    // sdp projection + residual h -> Kb (pre-BN1), fused BN1 stats
    gemm_bf16<64, 0, 1, 0, 1, 0><<<dim3(rt64, 1), 256, 0, stream>>>(
        HA16, N_NODES, 128, prep + (size_t)8 * 8192, 2, bsdp, h, Kb, 128, 0, 0, sums1, nullptr);

    bn_finalize<<<1, 128, 0, stream>>>(sums1, gamma, beta, ss1);

    // FFN1: T16 = relu(bn1(Kb) @ Wh1 + bh1), bf16 out — BN1 applied during A-staging
    gemm_bf16<128, 1, 0, 0, 0, 1><<<dim3(rt128, 2), 256, 0, stream>>>(
        Kb, N_NODES, 128, prep + (size_t)10 * 8192, 2, bh1, nullptr, T16, 256, 128, 1, nullptr, ss1);
    // FFN2: Kb = T16 @ Wh2 + bh2 + bn1(Kb) resid (f32 + ss), fused BN2 stats
    gemm_bf16<64, 0, 1, 2, 1, 0><<<dim3(rt64, 1), 256, 0, stream>>>(
        T16, N_NODES, 256, prep + (size_t)14 * 8192, 4, bh2, Kb, Kb, 128, 0, 0, sums2, ss1);

    bn_finalize<<<1, 128, 0, stream>>>(sums2, gamma, beta, ss2);
    bn_apply_f32<<<2048, 256, 0, stream>>>(Kb, ss2, out);
}

// Round 16
// 762.006 us; speedup vs baseline: 1.3003x; 1.3003x over previous
//
#include <hip/hip_runtime.h>
#include <hip/hip_bf16.h>
#include <math.h>

#define N_NODES 50000
#define E_EDGES 800000
#define D_DIM   128
#define H_HEADS 8

typedef __attribute__((ext_vector_type(8))) short short8;
typedef __attribute__((ext_vector_type(4))) float f32x4;
typedef unsigned int   uint_t;
typedef unsigned short ushort_t;

static __device__ __forceinline__ float4 ldg4(const float* p) {
    return *reinterpret_cast<const float4*>(p);
}
// f32 -> bf16 bits, round-to-nearest-even
static __device__ __forceinline__ ushort_t f2bf(float x) {
    union { float f; uint_t u; } v; v.f = x;
    uint_t r = v.u + 0x7fffu + ((v.u >> 16) & 1u);
    return (ushort_t)(r >> 16);
}
static __device__ __forceinline__ float bf2f(ushort_t b) {
    union { uint_t u; float f; } v; v.u = ((uint_t)b) << 16;
    return v.f;
}
static __device__ __forceinline__ uint_t pk(float lo, float hi) {
    return (uint_t)f2bf(lo) | ((uint_t)f2bf(hi) << 16);
}

// ---------------- CSR build ----------------
__global__ void hist_kernel(const int* __restrict__ dst, int* __restrict__ hist) {
    int i = blockIdx.x * blockDim.x + threadIdx.x;
    if (i < E_EDGES) atomicAdd(&hist[dst[i]], 1);
}

__global__ __launch_bounds__(1024) void scan_kernel(const int* __restrict__ cnt,
                                                    int* __restrict__ start,
                                                    int* __restrict__ cursor) {
    __shared__ int sh[1024];
    const int t = threadIdx.x;
    const int CPT = (N_NODES + 1023) / 1024;
    int lo = t * CPT;
    int hi = lo + CPT; if (hi > N_NODES) hi = N_NODES; if (lo > N_NODES) lo = N_NODES;
    int s = 0;
    for (int i = lo; i < hi; i++) s += cnt[i];
    sh[t] = s;
    __syncthreads();
    for (int off = 1; off < 1024; off <<= 1) {
        int v = (t >= off) ? sh[t - off] : 0;
        __syncthreads();
        sh[t] += v;
        __syncthreads();
    }
    int run = sh[t] - s;
    for (int i = lo; i < hi; i++) {
        start[i]  = run;
        cursor[i] = run;
        run += cnt[i];
    }
    if (t == 1023) start[N_NODES] = sh[1023];
}

__global__ void scatter_kernel(const int* __restrict__ src, const int* __restrict__ dst,
                               int* __restrict__ cursor,
                               int* __restrict__ rank, int* __restrict__ srcs) {
    int i = blockIdx.x * blockDim.x + threadIdx.x;
    if (i < E_EDGES) {
        int p = atomicAdd(&cursor[dst[i]], 1);
        rank[i] = p;
        srcs[p] = src[i];
    }
}

// ---------------- weight prep: bf16, transposed [col][k], XOR-swizzled, 16KB tiles ----------------
__global__ __launch_bounds__(256) void prep_weights(const float* __restrict__ Wq,
                                                    const float* __restrict__ Wk,
                                                    const float* __restrict__ Wv,
                                                    const float* __restrict__ We,
                                                    const float* __restrict__ Wsdp,
                                                    const float* __restrict__ Wh1,
                                                    const float* __restrict__ Wh2,
                                                    ushort_t* __restrict__ prep) {
    const int b = blockIdx.x;
    const float* W; int ld, cb, kc;
    if (b < 6)       { W = (b < 2 ? Wq : (b < 4 ? Wk : Wv)); ld = 128; cb = 0; kc = b & 1; }
    else if (b < 8)  { W = We;   ld = 128; cb = 0;            kc = b - 6; }
    else if (b < 10) { W = Wsdp; ld = 128; cb = 0;            kc = b - 8; }
    else if (b < 14) { W = Wh1;  ld = 256; cb = (b - 10) >> 1; kc = (b - 10) & 1; }
    else             { W = Wh2;  ld = 128; cb = 0;            kc = b - 14; }
    char* tile = (char*)(prep + (size_t)b * 8192);
    for (int i = threadIdx.x; i < 8192; i += 256) {
        int col = i >> 6, kl = i & 63;
        int k = kc * 64 + kl;
        float v = W[(size_t)k * ld + cb * 128 + col];
        int byte = (col * 128 + kl * 2) ^ ((col & 7) << 4);
        *(ushort_t*)(tile + byte) = f2bf(v);
    }
}

// ---------------- We in MFMA-fragment-linear layout (32KB) ----------------
__global__ __launch_bounds__(256) void prep_we_frag(const float* __restrict__ We,
                                                    ushort_t* __restrict__ WeF) {
    int slot = blockIdx.x * 256 + threadIdx.x;
    if (slot < 2048) {
        int lane = slot & 63;
        int kc   = (slot >> 6) & 3;
        int cg   = slot >> 8;
        int col  = cg * 16 + (lane & 15);
        int kb   = kc * 32 + ((lane >> 4) << 3);
#pragma unroll
        for (int j = 0; j < 8; j++)
            WeF[slot * 8 + j] = f2bf(We[(size_t)(kb + j) * 128 + col]);
    }
}

// ---------------- bf16 MFMA GEMM ----------------
// ROWS rows/block, 256 threads = 4 waves (2x2).
// OBF: bf16 out. ABF: bf16 A. RESMODE: 0=f32 resid, 1=bf16 resid, 2=f32 resid w/ scale-shift.
// SADD: per-col sum/sumsq accumulation. ASS: apply scale-shift to A (f32 path) during staging.
template<int ROWS, int OBF, int ABF, int RESMODE, int SADD, int ASS>
__global__ __launch_bounds__(256) void gemm_bf16(const void* __restrict__ Av,
                                                 int M, int K,
                                                 const ushort_t* __restrict__ Bt, int nkc,
                                                 const float* __restrict__ bias,
                                                 const void* __restrict__ residv,
                                                 void* __restrict__ Cv, int ldc,
                                                 size_t cbStride, int doRelu,
                                                 float* __restrict__ sums,
                                                 const float* __restrict__ ss) {
    constexpr int MI  = ROWS / 32;
    constexpr int TPR = 256 / ROWS;
    constexpr int KPT = 64 / TPR;
    __shared__ __align__(16) unsigned char As[ROWS * 128];
    __shared__ __align__(16) unsigned char Bs[16384];
    __shared__ float csum[128], csq[128];
    const int tid  = threadIdx.x;
    const int lane = tid & 63;
    const int wid  = tid >> 6;
    const int wr   = wid >> 1;
    const int wc   = wid & 1;
    const int cb   = blockIdx.y;
    const int row0 = blockIdx.x * ROWS;

    if (SADD && tid < 128) { csum[tid] = 0.f; csq[tid] = 0.f; }

    f32x4 acc[MI][4];
#pragma unroll
    for (int i = 0; i < MI; i++)
#pragma unroll
        for (int j = 0; j < 4; j++) acc[i][j] = (f32x4){0.f, 0.f, 0.f, 0.f};

    for (int kc = 0; kc < nkc; kc++) {
        __syncthreads();
        {   // stage A chunk: ROWS rows x 64 k
            int row = tid / TPR;
            int kl0 = (tid % TPR) * KPT;
            int gr  = row0 + row;
            int s = (row & 7) << 4;
            if (ABF) {
                const ushort_t* A16 = (const ushort_t*)Av;
#pragma unroll
                for (int j = 0; j < KPT / 8; j++) {
                    uint4 w = make_uint4(0, 0, 0, 0);
                    if (gr < M) w = *(const uint4*)(&A16[(size_t)gr * K + kc * 64 + kl0 + 8 * j]);
                    int byte = (row * 128 + (kl0 + 8 * j) * 2) ^ s;
                    *(uint4*)(As + byte) = w;
                }
            } else {
                const float* A = (const float*)Av;
                float4 v4[KPT / 4];
                if (gr < M) {
                    const float* ap = &A[(size_t)gr * K + kc * 64 + kl0];
#pragma unroll
                    for (int j = 0; j < KPT / 4; j++) v4[j] = ldg4(ap + 4 * j);
                } else {
#pragma unroll
                    for (int j = 0; j < KPT / 4; j++) v4[j] = make_float4(0.f, 0.f, 0.f, 0.f);
                }
                if (ASS) {
#pragma unroll
                    for (int j = 0; j < KPT / 4; j++) {
                        int kk = kc * 64 + kl0 + 4 * j;
                        v4[j].x = v4[j].x * ss[kk + 0] + ss[128 + kk + 0];
                        v4[j].y = v4[j].y * ss[kk + 1] + ss[128 + kk + 1];
                        v4[j].z = v4[j].z * ss[kk + 2] + ss[128 + kk + 2];
                        v4[j].w = v4[j].w * ss[kk + 3] + ss[128 + kk + 3];
                    }
                }
#pragma unroll
                for (int j = 0; j < KPT / 8; j++) {
                    uint4 w;
                    w.x = pk(v4[2 * j].x, v4[2 * j].y);
                    w.y = pk(v4[2 * j].z, v4[2 * j].w);
                    w.z = pk(v4[2 * j + 1].x, v4[2 * j + 1].y);
                    w.w = pk(v4[2 * j + 1].z, v4[2 * j + 1].w);
                    int byte = (row * 128 + (kl0 + 8 * j) * 2) ^ s;
                    *(uint4*)(As + byte) = w;
                }
            }
        }
        {   // stage B chunk: linear 16KB copy of prepped tile
            const uint4* gB = (const uint4*)(Bt + (size_t)(cb * nkc + kc) * 8192);
#pragma unroll
            for (int j = 0; j < 4; j++) {
                int idx = j * 256 + tid;
                ((uint4*)Bs)[idx] = gB[idx];
            }
        }
        __syncthreads();
#pragma unroll
        for (int k0 = 0; k0 < 64; k0 += 32) {
            short8 a[MI], b[4];
#pragma unroll
            for (int mi = 0; mi < MI; mi++) {
                int row = wr * (ROWS / 2) + mi * 16 + (lane & 15);
                int byte = (row * 128 + k0 * 2 + (lane >> 4) * 16) ^ ((row & 7) << 4);
                a[mi] = *(const short8*)(As + byte);
            }
#pragma unroll
            for (int ni = 0; ni < 4; ni++) {
                int col = wc * 64 + ni * 16 + (lane & 15);
                int byte = (col * 128 + k0 * 2 + (lane >> 4) * 16) ^ ((col & 7) << 4);
                b[ni] = *(const short8*)(Bs + byte);
            }
#pragma unroll
            for (int mi = 0; mi < MI; mi++)
#pragma unroll
                for (int ni = 0; ni < 4; ni++)
                    acc[mi][ni] = __builtin_amdgcn_mfma_f32_16x16x32_bf16(a[mi], b[ni], acc[mi][ni], 0, 0, 0);
        }
    }

    float colS[4] = {0.f, 0.f, 0.f, 0.f};
    float colQ[4] = {0.f, 0.f, 0.f, 0.f};
#pragma unroll
    for (int mi = 0; mi < MI; mi++) {
#pragma unroll
        for (int r = 0; r < 4; r++) {
            int row = row0 + wr * (ROWS / 2) + mi * 16 + ((lane >> 4) << 2) + r;
            if (row < M) {
#pragma unroll
                for (int ni = 0; ni < 4; ni++) {
                    int col = wc * 64 + ni * 16 + (lane & 15);
                    float v = acc[mi][ni][r];
                    if (bias) v += bias[cb * 128 + col];
                    if (doRelu) v = fmaxf(v, 0.f);
                    if (residv) {
                        if (RESMODE == 1) {
                            v += bf2f(((const ushort_t*)residv)[(size_t)row * ldc + col]);
                        } else if (RESMODE == 2) {
                            float rr = ((const float*)residv)[(size_t)row * ldc + col];
                            v += rr * ss[col] + ss[128 + col];
                        } else {
                            v += ((const float*)residv)[(size_t)row * ldc + col];
                        }
                    }
                    if (SADD) { colS[ni] += v; colQ[ni] += v * v; }
                    if (OBF) ((ushort_t*)Cv)[cb * cbStride + (size_t)row * ldc + col] = f2bf(v);
                    else     ((float*)Cv)[cb * cbStride + (size_t)row * ldc + col] = v;
                }
            }
        }
    }
    if (SADD) {
#pragma unroll
        for (int ni = 0; ni < 4; ni++) {
            int col = wc * 64 + ni * 16 + (lane & 15);
            atomicAdd(&csum[col], colS[ni]);
            atomicAdd(&csq[col],  colQ[ni]);
        }
        __syncthreads();
        if (tid < 128) {
            atomicAdd(&sums[tid],       csum[tid]);
            atomicAdd(&sums[128 + tid], csq[tid]);
        }
    }
}

// ---------------- fused edge kernel (round-9 champion structure, verbatim) ----------------
// 512 threads = 8 waves (2 row-groups x 4 head-pair groups); 64 edges/block; single tile.
// Gathers in epilogue; f32 sm; 32B sector-aligned sorted S stores. No cross-barrier carries.
__global__ __launch_bounds__(512, 8) void edge_mfma(const float* __restrict__ e,
                                                    const int* __restrict__ src,
                                                    const int* __restrict__ dst,
                                                    const ushort_t* __restrict__ Qm,
                                                    const ushort_t* __restrict__ Km,
                                                    const ushort_t* __restrict__ WeF,
                                                    const int* __restrict__ rank,
                                                    float* __restrict__ S,
                                                    float* __restrict__ out_e) {
    __shared__ __align__(16) unsigned char Asm[16384];  // 2 chunks x [64 rows][64 k] bf16 swizzled
    __shared__ float sm[64][8];                          // [edge-in-tile][head]
    const int tid  = threadIdx.x;
    const int lane = tid & 63;
    const int wid  = tid >> 6;
    const int wr   = wid >> 2;       // 0..1 : rows wr*32
    const int wc   = wid & 3;        // 0..3 : heads 2wc, 2wc+1
    const int e0   = blockIdx.x * 64;

    {   // stage e tile (f32 -> bf16 LDS) + f32 pass-through copy
        int row = tid >> 3;
        int c0  = (tid & 7) * 16;
        const float* ep = &e[(size_t)(e0 + row) * 128 + c0];
        float*       op = &out_e[(size_t)(e0 + row) * 128 + c0];
        float4 v4[4];
#pragma unroll
        for (int j = 0; j < 4; j++) v4[j] = ldg4(ep + 4 * j);
#pragma unroll
        for (int j = 0; j < 4; j++) *(float4*)(op + 4 * j) = v4[j];
        int chunk = c0 >> 6;
        int klb   = (c0 & 63) * 2;
        int s     = (row & 7) << 4;
        uint4 w0, w1;
        w0.x = pk(v4[0].x, v4[0].y); w0.y = pk(v4[0].z, v4[0].w);
        w0.z = pk(v4[1].x, v4[1].y); w0.w = pk(v4[1].z, v4[1].w);
        w1.x = pk(v4[2].x, v4[2].y); w1.y = pk(v4[2].z, v4[2].w);
        w1.z = pk(v4[3].x, v4[3].y); w1.w = pk(v4[3].z, v4[3].w);
        *(uint4*)(Asm + chunk * 8192 + ((row * 128 + klb) ^ s))      = w0;
        *(uint4*)(Asm + chunk * 8192 + ((row * 128 + klb + 16) ^ s)) = w1;
    }
    __syncthreads();

    f32x4 acc[2][2];
#pragma unroll
    for (int i = 0; i < 2; i++)
#pragma unroll
        for (int j = 0; j < 2; j++) acc[i][j] = (f32x4){0.f, 0.f, 0.f, 0.f};

#pragma unroll
    for (int k0 = 0; k0 < 128; k0 += 32) {
        int chunk = k0 >> 6;
        int klb   = (k0 & 63) * 2;
        int kc    = k0 >> 5;
        short8 a[2];
#pragma unroll
        for (int mi = 0; mi < 2; mi++) {
            int arow = wr * 32 + mi * 16 + (lane & 15);
            int byte = chunk * 8192 + ((arow * 128 + klb + (lane >> 4) * 16) ^ ((arow & 7) << 4));
            a[mi] = *(const short8*)(Asm + byte);
        }
#pragma unroll
        for (int ni = 0; ni < 2; ni++) {
            int cg = wc * 2 + ni;
            short8 b = *(const short8*)(WeF + ((size_t)((cg * 4 + kc) * 64 + lane)) * 8);
#pragma unroll
            for (int mi = 0; mi < 2; mi++)
                acc[mi][ni] = __builtin_amdgcn_mfma_f32_16x16x32_bf16(a[mi], b, acc[mi][ni], 0, 0, 0);
        }
    }

    // epilogue: gather bf16 K[src]*Q[dst], 16-lane reduce, exp -> LDS
#pragma unroll
    for (int mi = 0; mi < 2; mi++) {
        int rows[4], sidx[4], didx[4];
#pragma unroll
        for (int r = 0; r < 4; r++) {
            rows[r] = e0 + wr * 32 + mi * 16 + ((lane >> 4) << 2) + r;
            sidx[r] = src[rows[r]];
            didx[r] = dst[rows[r]];
        }
#pragma unroll
        for (int ni = 0; ni < 2; ni++) {
            int head = wc * 2 + ni;
            int col  = head * 16 + (lane & 15);
            float pv[4];
#pragma unroll
            for (int r = 0; r < 4; r++) {
                float kv = bf2f(Km[(size_t)sidx[r] * 128 + col]);
                float qv = bf2f(Qm[(size_t)didx[r] * 128 + col]);
                pv[r] = acc[mi][ni][r] * kv * qv;
            }
#pragma unroll
            for (int off = 1; off < 16; off <<= 1)
#pragma unroll
                for (int r = 0; r < 4; r++) pv[r] += __shfl_xor(pv[r], off, 64);
            if ((lane & 15) == 0) {
#pragma unroll
                for (int r = 0; r < 4; r++) {
                    float v = fminf(fmaxf(0.25f * pv[r], -5.f), 5.f);
                    sm[rows[r] - e0][head] = __expf(v);
                }
            }
        }
    }
    __syncthreads();
    // sorted, contiguous 32B f32 store per edge (sector-aligned)
    if (tid < 64) {
        int rk = rank[e0 + tid];
        float4 a0 = *(const float4*)&sm[tid][0];
        float4 a1 = *(const float4*)&sm[tid][4];
        *(float4*)&S[(size_t)rk * 8]     = a0;
        *(float4*)&S[(size_t)rk * 8 + 4] = a1;
    }
}

// ---------------- aggregation: wave-per-node, f32 S + bf16 V, bf16 output ----------------
__global__ __launch_bounds__(256) void agg_kernel(const uint_t* __restrict__ Vu,
                                                  const float* __restrict__ S,
                                                  const int* __restrict__ start,
                                                  const int* __restrict__ srcs,
                                                  uint_t* __restrict__ HAu) {
    const int lane = threadIdx.x & 63;
    const int n = blockIdx.x * 4 + (threadIdx.x >> 6);
    if (n >= N_NODES) return;
    const int s0 = start[n];
    const int s1 = start[n + 1];
    const int h  = lane >> 3;
    float a0 = 0.f, a1 = 0.f, z = 0.f;
    int i = s0;
    for (; i + 4 <= s1; i += 4) {
        int m0 = srcs[i], m1 = srcs[i + 1], m2 = srcs[i + 2], m3 = srcs[i + 3];
        float t0 = S[(size_t)i * 8 + h];
        float t1 = S[(size_t)(i + 1) * 8 + h];
        float t2 = S[(size_t)(i + 2) * 8 + h];
        float t3 = S[(size_t)(i + 3) * 8 + h];
        uint_t v0 = Vu[(size_t)m0 * 64 + lane];
        uint_t v1 = Vu[(size_t)m1 * 64 + lane];
        uint_t v2 = Vu[(size_t)m2 * 64 + lane];
        uint_t v3 = Vu[(size_t)m3 * 64 + lane];
        a0 = fmaf(t0, bf2f((ushort_t)v0), a0); a1 = fmaf(t0, bf2f((ushort_t)(v0 >> 16)), a1);
        a0 = fmaf(t1, bf2f((ushort_t)v1), a0); a1 = fmaf(t1, bf2f((ushort_t)(v1 >> 16)), a1);
        a0 = fmaf(t2, bf2f((ushort_t)v2), a0); a1 = fmaf(t2, bf2f((ushort_t)(v2 >> 16)), a1);
        a0 = fmaf(t3, bf2f((ushort_t)v3), a0); a1 = fmaf(t3, bf2f((ushort_t)(v3 >> 16)), a1);
        z += t0 + t1 + t2 + t3;
    }
    for (; i < s1; i++) {
        int m = srcs[i];
        float t = S[(size_t)i * 8 + h];
        uint_t v = Vu[(size_t)m * 64 + lane];
        a0 = fmaf(t, bf2f((ushort_t)v), a0);
        a1 = fmaf(t, bf2f((ushort_t)(v >> 16)), a1);
        z += t;
    }
    float inv = 1.f / (z + 1e-6f);
    HAu[(size_t)n * 64 + lane] = pk(a0 * inv, a1 * inv);
}

// ---------------- batch norm: finalize sums -> scale/shift; apply y = x*scale+shift ----------------
__global__ void bn_finalize(const float* __restrict__ sums,
                            const float* __restrict__ gamma,
                            const float* __restrict__ beta,
                            float* __restrict__ ss) {
    int c = threadIdx.x;   // 128
    float mu  = sums[c] * (1.f / (float)N_NODES);
    float var = sums[128 + c] * (1.f / (float)N_NODES) - mu * mu;
    float scale = rsqrtf(var + 1e-5f) * gamma[c];
    ss[c]       = scale;
    ss[128 + c] = beta[c] - mu * scale;
}

__global__ __launch_bounds__(256) void bn_apply_f32(const float* __restrict__ X,
                                                    const float* __restrict__ ss,
                                                    float* __restrict__ Y) {
    const size_t total = (size_t)N_NODES * 128;
    const size_t step = (size_t)gridDim.x * blockDim.x * 4;
    for (size_t i = ((size_t)blockIdx.x * blockDim.x + threadIdx.x) * 4; i < total; i += step) {
        float4 x = ldg4(&X[i]);
        int c = (int)(i & 127);
        float4 y;
        y.x = x.x * ss[c + 0] + ss[128 + c + 0];
        y.y = x.y * ss[c + 1] + ss[128 + c + 1];
        y.z = x.z * ss[c + 2] + ss[128 + c + 2];
        y.w = x.w * ss[c + 3] + ss[128 + c + 3];
        *(float4*)(&Y[i]) = y;
    }
}

extern "C" void kernel_launch(void* const* d_in, const int* in_sizes, int n_in,
                              void* d_out, int out_size, void* d_ws, size_t ws_size,
                              hipStream_t stream) {
    (void)in_sizes; (void)n_in; (void)out_size; (void)ws_size;
    const int*   src   = (const int*)d_in[0];
    const int*   dst   = (const int*)d_in[1];
    const float* h     = (const float*)d_in[2];
    const float* e     = (const float*)d_in[3];
    const float* Wq    = (const float*)d_in[5];
    const float* Wk    = (const float*)d_in[6];
    const float* Wv    = (const float*)d_in[7];
    const float* We    = (const float*)d_in[8];
    const float* Wsdp  = (const float*)d_in[9];
    const float* bsdp  = (const float*)d_in[10];
    const float* Wh1   = (const float*)d_in[11];
    const float* bh1   = (const float*)d_in[12];
    const float* Wh2   = (const float*)d_in[13];
    const float* bh2   = (const float*)d_in[14];
    const float* gamma = (const float*)d_in[15];
    const float* beta  = (const float*)d_in[16];
    float* out = (float*)d_out;

    float* ws = (float*)d_ws;
    const size_t NM = (size_t)N_NODES * 128;   // 6.4M elements
    ushort_t* Q16  = (ushort_t*)ws;
    ushort_t* K16  = Q16 + NM;
    ushort_t* V16  = Q16 + 2 * NM;
    ushort_t* HA16 = (ushort_t*)(ws + 3 * NM / 2);
    float*    Kb   = ws + 2 * NM;
    float*    Sb   = ws + 3 * NM;   // f32 scores, sorted, [pos][8]
    float*    T1r  = ws + 4 * NM;
    ushort_t* T16  = (ushort_t*)T1r;
    float*    STATS = ws + 6 * NM;
    int* hist   = (int*)(STATS + 1024);
    int* startp = hist + N_NODES;
    int* cursor = startp + N_NODES + 1;
    ushort_t* prep = (ushort_t*)(((uintptr_t)(cursor + N_NODES) + 255) & ~(uintptr_t)255);
    ushort_t* WeF  = prep + (size_t)18 * 8192;

    int* rank = (int*)T1r;
    int* srcs = rank + E_EDGES;

    float* sums1 = STATS;
    float* ss1   = STATS + 256;
    float* sums2 = STATS + 512;
    float* ss2   = STATS + 768;

    prep_weights<<<18, 256, 0, stream>>>(Wq, Wk, Wv, We, Wsdp, Wh1, Wh2, prep);
    prep_we_frag<<<8, 256, 0, stream>>>(We, WeF);

    hipMemsetAsync(STATS, 0, (1024 + N_NODES) * sizeof(float), stream);

    hist_kernel<<<(E_EDGES + 255) / 256, 256, 0, stream>>>(dst, hist);
    scan_kernel<<<1, 1024, 0, stream>>>(hist, startp, cursor);
    scatter_kernel<<<(E_EDGES + 255) / 256, 256, 0, stream>>>(src, dst, cursor, rank, srcs);

    const int rt128 = (N_NODES + 127) / 128;   // 391
    const int rt64  = (N_NODES + 63) / 64;     // 782

    // q,k,v (bf16 out): cb = matrix (Q16,K16,V16)
    gemm_bf16<128, 1, 0, 0, 0, 0><<<dim3(rt128, 3), 256, 0, stream>>>(
        h, N_NODES, 128, prep, 2, nullptr, nullptr, Q16, 128, NM, 0, nullptr, nullptr);

    // fused edge scores (sorted f32 S, [pos][8]) + e pass-through copy — round-9 champion
    edge_mfma<<<E_EDGES / 64, 512, 0, stream>>>(e, src, dst, Q16, K16, WeF,
                                                rank, Sb, out + NM);

    // aggregation -> h_attn bf16
    agg_kernel<<<(N_NODES + 3) / 4, 256, 0, stream>>>((const uint_t*)V16, Sb, startp, srcs,
                                                      (uint_t*)HA16);

    // sdp projection + residual h -> Kb (pre-BN1), fused BN1 stats
    gemm_bf16<64, 0, 1, 0, 1, 0><<<dim3(rt64, 1), 256, 0, stream>>>(
        HA16, N_NODES, 128, prep + (size_t)8 * 8192, 2, bsdp, h, Kb, 128, 0, 0, sums1, nullptr);

    bn_finalize<<<1, 128, 0, stream>>>(sums1, gamma, beta, ss1);

    // FFN1: T16 = relu(bn1(Kb) @ Wh1 + bh1), bf16 out — BN1 applied during A-staging
    gemm_bf16<128, 1, 0, 0, 0, 1><<<dim3(rt128, 2), 256, 0, stream>>>(
        Kb, N_NODES, 128, prep + (size_t)10 * 8192, 2, bh1, nullptr, T16, 256, 128, 1, nullptr, ss1);
    // FFN2: Kb = T16 @ Wh2 + bh2 + bn1(Kb) resid (f32 + ss), fused BN2 stats
    gemm_bf16<64, 0, 1, 2, 1, 0><<<dim3(rt64, 1), 256, 0, stream>>>(
        T16, N_NODES, 256, prep + (size_t)14 * 8192, 4, bh2, Kb, Kb, 128, 0, 0, sums2, ss1);

    bn_finalize<<<1, 128, 0, stream>>>(sums2, gamma, beta, ss2);
    bn_apply_f32<<<2048, 256, 0, stream>>>(Kb, ss2, out);
}

// Round 17
// 753.443 us; speedup vs baseline: 1.3150x; 1.0114x over previous
//
#include <hip/hip_runtime.h>
#include <hip/hip_bf16.h>
#include <math.h>

#define N_NODES 50000
#define E_EDGES 800000
#define D_DIM   128
#define H_HEADS 8

typedef __attribute__((ext_vector_type(8))) short short8;
typedef __attribute__((ext_vector_type(4))) float f32x4;
typedef unsigned int   uint_t;
typedef unsigned short ushort_t;

static __device__ __forceinline__ float4 ldg4(const float* p) {
    return *reinterpret_cast<const float4*>(p);
}
// f32 -> bf16 bits, round-to-nearest-even
static __device__ __forceinline__ ushort_t f2bf(float x) {
    union { float f; uint_t u; } v; v.f = x;
    uint_t r = v.u + 0x7fffu + ((v.u >> 16) & 1u);
    return (ushort_t)(r >> 16);
}
static __device__ __forceinline__ float bf2f(ushort_t b) {
    union { uint_t u; float f; } v; v.u = ((uint_t)b) << 16;
    return v.f;
}
static __device__ __forceinline__ uint_t pk(float lo, float hi) {
    return (uint_t)f2bf(lo) | ((uint_t)f2bf(hi) << 16);
}

// ---------------- CSR build ----------------
__global__ void hist_kernel(const int* __restrict__ dst, int* __restrict__ hist) {
    int i = blockIdx.x * blockDim.x + threadIdx.x;
    if (i < E_EDGES) atomicAdd(&hist[dst[i]], 1);
}

__global__ __launch_bounds__(1024) void scan_kernel(const int* __restrict__ cnt,
                                                    int* __restrict__ start,
                                                    int* __restrict__ cursor) {
    __shared__ int sh[1024];
    const int t = threadIdx.x;
    const int CPT = (N_NODES + 1023) / 1024;
    int lo = t * CPT;
    int hi = lo + CPT; if (hi > N_NODES) hi = N_NODES; if (lo > N_NODES) lo = N_NODES;
    int s = 0;
    for (int i = lo; i < hi; i++) s += cnt[i];
    sh[t] = s;
    __syncthreads();
    for (int off = 1; off < 1024; off <<= 1) {
        int v = (t >= off) ? sh[t - off] : 0;
        __syncthreads();
        sh[t] += v;
        __syncthreads();
    }
    int run = sh[t] - s;
    for (int i = lo; i < hi; i++) {
        start[i]  = run;
        cursor[i] = run;
        run += cnt[i];
    }
    if (t == 1023) start[N_NODES] = sh[1023];
}

__global__ void scatter_kernel(const int* __restrict__ src, const int* __restrict__ dst,
                               int* __restrict__ cursor,
                               int* __restrict__ rank, int* __restrict__ srcs) {
    int i = blockIdx.x * blockDim.x + threadIdx.x;
    if (i < E_EDGES) {
        int p = atomicAdd(&cursor[dst[i]], 1);
        rank[i] = p;
        srcs[p] = src[i];
    }
}

// ---------------- weight prep: bf16, transposed [col][k], XOR-swizzled, 16KB tiles ----------------
__global__ __launch_bounds__(256) void prep_weights(const float* __restrict__ Wq,
                                                    const float* __restrict__ Wk,
                                                    const float* __restrict__ Wv,
                                                    const float* __restrict__ We,
                                                    const float* __restrict__ Wsdp,
                                                    const float* __restrict__ Wh1,
                                                    const float* __restrict__ Wh2,
                                                    ushort_t* __restrict__ prep) {
    const int b = blockIdx.x;
    const float* W; int ld, cb, kc;
    if (b < 6)       { W = (b < 2 ? Wq : (b < 4 ? Wk : Wv)); ld = 128; cb = 0; kc = b & 1; }
    else if (b < 8)  { W = We;   ld = 128; cb = 0;            kc = b - 6; }
    else if (b < 10) { W = Wsdp; ld = 128; cb = 0;            kc = b - 8; }
    else if (b < 14) { W = Wh1;  ld = 256; cb = (b - 10) >> 1; kc = (b - 10) & 1; }
    else             { W = Wh2;  ld = 128; cb = 0;            kc = b - 14; }
    char* tile = (char*)(prep + (size_t)b * 8192);
    for (int i = threadIdx.x; i < 8192; i += 256) {
        int col = i >> 6, kl = i & 63;
        int k = kc * 64 + kl;
        float v = W[(size_t)k * ld + cb * 128 + col];
        int byte = (col * 128 + kl * 2) ^ ((col & 7) << 4);
        *(ushort_t*)(tile + byte) = f2bf(v);
    }
}

// ---------------- We in MFMA-fragment-linear layout (32KB) ----------------
__global__ __launch_bounds__(256) void prep_we_frag(const float* __restrict__ We,
                                                    ushort_t* __restrict__ WeF) {
    int slot = blockIdx.x * 256 + threadIdx.x;
    if (slot < 2048) {
        int lane = slot & 63;
        int kc   = (slot >> 6) & 3;
        int cg   = slot >> 8;
        int col  = cg * 16 + (lane & 15);
        int kb   = kc * 32 + ((lane >> 4) << 3);
#pragma unroll
        for (int j = 0; j < 8; j++)
            WeF[slot * 8 + j] = f2bf(We[(size_t)(kb + j) * 128 + col]);
    }
}

// ---------------- fused QKV: stage h tile once, loop 3 weight matrices ----------------
// 64 rows/block, 256 threads = 4 waves (2x2); bf16 outputs at C + m*NM.
__global__ __launch_bounds__(256) void qkv_fused(const float* __restrict__ A,
                                                 const ushort_t* __restrict__ Bt,
                                                 ushort_t* __restrict__ C, int M) {
    __shared__ __align__(16) unsigned char As[2][8192];    // 2 k-chunks x [64 rows][64 k]
    __shared__ __align__(16) unsigned char Bs[2][16384];   // 2 k-chunks x [128 cols][64 k]
    const int tid  = threadIdx.x;
    const int lane = tid & 63;
    const int wid  = tid >> 6;
    const int wr   = wid >> 1;
    const int wc   = wid & 1;
    const int row0 = blockIdx.x * 64;
    const size_t NM = (size_t)N_NODES * 128;

    {   // stage A (both k-chunks) once
        int row = tid >> 2;          // 0..63
        int kl0 = (tid & 3) * 16;
        int gr  = row0 + row;
        int s   = (row & 7) << 4;
#pragma unroll
        for (int kc = 0; kc < 2; kc++) {
            float4 v4[4];
            if (gr < M) {
                const float* ap = &A[(size_t)gr * 128 + kc * 64 + kl0];
#pragma unroll
                for (int j = 0; j < 4; j++) v4[j] = ldg4(ap + 4 * j);
            } else {
#pragma unroll
                for (int j = 0; j < 4; j++) v4[j] = make_float4(0.f, 0.f, 0.f, 0.f);
            }
#pragma unroll
            for (int j = 0; j < 2; j++) {
                uint4 w;
                w.x = pk(v4[2 * j].x, v4[2 * j].y);
                w.y = pk(v4[2 * j].z, v4[2 * j].w);
                w.z = pk(v4[2 * j + 1].x, v4[2 * j + 1].y);
                w.w = pk(v4[2 * j + 1].z, v4[2 * j + 1].w);
                int byte = (row * 128 + (kl0 + 8 * j) * 2) ^ s;
                *(uint4*)(As[kc] + byte) = w;
            }
        }
    }

    for (int m = 0; m < 3; m++) {
        if (m) __syncthreads();               // Bs reads of prev iter complete
        {   // stage B (both k-chunks) for matrix m
            const uint4* g0 = (const uint4*)(Bt + (size_t)(m * 2 + 0) * 8192);
            const uint4* g1 = (const uint4*)(Bt + (size_t)(m * 2 + 1) * 8192);
#pragma unroll
            for (int j = 0; j < 4; j++) {
                ((uint4*)Bs[0])[j * 256 + tid] = g0[j * 256 + tid];
                ((uint4*)Bs[1])[j * 256 + tid] = g1[j * 256 + tid];
            }
        }
        __syncthreads();

        f32x4 acc[2][4];
#pragma unroll
        for (int i = 0; i < 2; i++)
#pragma unroll
            for (int j = 0; j < 4; j++) acc[i][j] = (f32x4){0.f, 0.f, 0.f, 0.f};

#pragma unroll
        for (int kc = 0; kc < 2; kc++) {
#pragma unroll
            for (int k0 = 0; k0 < 64; k0 += 32) {
                short8 a[2], b[4];
#pragma unroll
                for (int mi = 0; mi < 2; mi++) {
                    int arow = wr * 32 + mi * 16 + (lane & 15);
                    int byte = (arow * 128 + k0 * 2 + (lane >> 4) * 16) ^ ((arow & 7) << 4);
                    a[mi] = *(const short8*)(As[kc] + byte);
                }
#pragma unroll
                for (int ni = 0; ni < 4; ni++) {
                    int col = wc * 64 + ni * 16 + (lane & 15);
                    int byte = (col * 128 + k0 * 2 + (lane >> 4) * 16) ^ ((col & 7) << 4);
                    b[ni] = *(const short8*)(Bs[kc] + byte);
                }
#pragma unroll
                for (int mi = 0; mi < 2; mi++)
#pragma unroll
                    for (int ni = 0; ni < 4; ni++)
                        acc[mi][ni] = __builtin_amdgcn_mfma_f32_16x16x32_bf16(a[mi], b[ni], acc[mi][ni], 0, 0, 0);
            }
        }
        // epilogue: bf16 store to matrix m
#pragma unroll
        for (int mi = 0; mi < 2; mi++) {
#pragma unroll
            for (int r = 0; r < 4; r++) {
                int row = row0 + wr * 32 + mi * 16 + ((lane >> 4) << 2) + r;
                if (row < M) {
#pragma unroll
                    for (int ni = 0; ni < 4; ni++) {
                        int col = wc * 64 + ni * 16 + (lane & 15);
                        C[(size_t)m * NM + (size_t)row * 128 + col] = f2bf(acc[mi][ni][r]);
                    }
                }
            }
        }
    }
}

// ---------------- bf16 MFMA GEMM ----------------
// ROWS rows/block, 256 threads = 4 waves (2x2).
// OBF: bf16 out. ABF: bf16 A. RESMODE: 0=f32 resid, 1=bf16 resid, 2=f32 resid w/ scale-shift.
// SADD: per-col sum/sumsq accumulation. ASS: apply scale-shift to A (f32 path) during staging.
template<int ROWS, int OBF, int ABF, int RESMODE, int SADD, int ASS>
__global__ __launch_bounds__(256) void gemm_bf16(const void* __restrict__ Av,
                                                 int M, int K,
                                                 const ushort_t* __restrict__ Bt, int nkc,
                                                 const float* __restrict__ bias,
                                                 const void* __restrict__ residv,
                                                 void* __restrict__ Cv, int ldc,
                                                 size_t cbStride, int doRelu,
                                                 float* __restrict__ sums,
                                                 const float* __restrict__ ss) {
    constexpr int MI  = ROWS / 32;
    constexpr int TPR = 256 / ROWS;
    constexpr int KPT = 64 / TPR;
    __shared__ __align__(16) unsigned char As[ROWS * 128];
    __shared__ __align__(16) unsigned char Bs[16384];
    __shared__ float csum[128], csq[128];
    const int tid  = threadIdx.x;
    const int lane = tid & 63;
    const int wid  = tid >> 6;
    const int wr   = wid >> 1;
    const int wc   = wid & 1;
    const int cb   = blockIdx.y;
    const int row0 = blockIdx.x * ROWS;

    if (SADD && tid < 128) { csum[tid] = 0.f; csq[tid] = 0.f; }

    f32x4 acc[MI][4];
#pragma unroll
    for (int i = 0; i < MI; i++)
#pragma unroll
        for (int j = 0; j < 4; j++) acc[i][j] = (f32x4){0.f, 0.f, 0.f, 0.f};

    for (int kc = 0; kc < nkc; kc++) {
        __syncthreads();
        {   // stage A chunk: ROWS rows x 64 k
            int row = tid / TPR;
            int kl0 = (tid % TPR) * KPT;
            int gr  = row0 + row;
            int s = (row & 7) << 4;
            if (ABF) {
                const ushort_t* A16 = (const ushort_t*)Av;
#pragma unroll
                for (int j = 0; j < KPT / 8; j++) {
                    uint4 w = make_uint4(0, 0, 0, 0);
                    if (gr < M) w = *(const uint4*)(&A16[(size_t)gr * K + kc * 64 + kl0 + 8 * j]);
                    int byte = (row * 128 + (kl0 + 8 * j) * 2) ^ s;
                    *(uint4*)(As + byte) = w;
                }
            } else {
                const float* A = (const float*)Av;
                float4 v4[KPT / 4];
                if (gr < M) {
                    const float* ap = &A[(size_t)gr * K + kc * 64 + kl0];
#pragma unroll
                    for (int j = 0; j < KPT / 4; j++) v4[j] = ldg4(ap + 4 * j);
                } else {
#pragma unroll
                    for (int j = 0; j < KPT / 4; j++) v4[j] = make_float4(0.f, 0.f, 0.f, 0.f);
                }
                if (ASS) {
#pragma unroll
                    for (int j = 0; j < KPT / 4; j++) {
                        int kk = kc * 64 + kl0 + 4 * j;
                        v4[j].x = v4[j].x * ss[kk + 0] + ss[128 + kk + 0];
                        v4[j].y = v4[j].y * ss[kk + 1] + ss[128 + kk + 1];
                        v4[j].z = v4[j].z * ss[kk + 2] + ss[128 + kk + 2];
                        v4[j].w = v4[j].w * ss[kk + 3] + ss[128 + kk + 3];
                    }
                }
#pragma unroll
                for (int j = 0; j < KPT / 8; j++) {
                    uint4 w;
                    w.x = pk(v4[2 * j].x, v4[2 * j].y);
                    w.y = pk(v4[2 * j].z, v4[2 * j].w);
                    w.z = pk(v4[2 * j + 1].x, v4[2 * j + 1].y);
                    w.w = pk(v4[2 * j + 1].z, v4[2 * j + 1].w);
                    int byte = (row * 128 + (kl0 + 8 * j) * 2) ^ s;
                    *(uint4*)(As + byte) = w;
                }
            }
        }
        {   // stage B chunk: linear 16KB copy of prepped tile
            const uint4* gB = (const uint4*)(Bt + (size_t)(cb * nkc + kc) * 8192);
#pragma unroll
            for (int j = 0; j < 4; j++) {
                int idx = j * 256 + tid;
                ((uint4*)Bs)[idx] = gB[idx];
            }
        }
        __syncthreads();
#pragma unroll
        for (int k0 = 0; k0 < 64; k0 += 32) {
            short8 a[MI], b[4];
#pragma unroll
            for (int mi = 0; mi < MI; mi++) {
                int row = wr * (ROWS / 2) + mi * 16 + (lane & 15);
                int byte = (row * 128 + k0 * 2 + (lane >> 4) * 16) ^ ((row & 7) << 4);
                a[mi] = *(const short8*)(As + byte);
            }
#pragma unroll
            for (int ni = 0; ni < 4; ni++) {
                int col = wc * 64 + ni * 16 + (lane & 15);
                int byte = (col * 128 + k0 * 2 + (lane >> 4) * 16) ^ ((col & 7) << 4);
                b[ni] = *(const short8*)(Bs + byte);
            }
#pragma unroll
            for (int mi = 0; mi < MI; mi++)
#pragma unroll
                for (int ni = 0; ni < 4; ni++)
                    acc[mi][ni] = __builtin_amdgcn_mfma_f32_16x16x32_bf16(a[mi], b[ni], acc[mi][ni], 0, 0, 0);
        }
    }

    float colS[4] = {0.f, 0.f, 0.f, 0.f};
    float colQ[4] = {0.f, 0.f, 0.f, 0.f};
#pragma unroll
    for (int mi = 0; mi < MI; mi++) {
#pragma unroll
        for (int r = 0; r < 4; r++) {
            int row = row0 + wr * (ROWS / 2) + mi * 16 + ((lane >> 4) << 2) + r;
            if (row < M) {
#pragma unroll
                for (int ni = 0; ni < 4; ni++) {
                    int col = wc * 64 + ni * 16 + (lane & 15);
                    float v = acc[mi][ni][r];
                    if (bias) v += bias[cb * 128 + col];
                    if (doRelu) v = fmaxf(v, 0.f);
                    if (residv) {
                        if (RESMODE == 1) {
                            v += bf2f(((const ushort_t*)residv)[(size_t)row * ldc + col]);
                        } else if (RESMODE == 2) {
                            float rr = ((const float*)residv)[(size_t)row * ldc + col];
                            v += rr * ss[col] + ss[128 + col];
                        } else {
                            v += ((const float*)residv)[(size_t)row * ldc + col];
                        }
                    }
                    if (SADD) { colS[ni] += v; colQ[ni] += v * v; }
                    if (OBF) ((ushort_t*)Cv)[cb * cbStride + (size_t)row * ldc + col] = f2bf(v);
                    else     ((float*)Cv)[cb * cbStride + (size_t)row * ldc + col] = v;
                }
            }
        }
    }
    if (SADD) {
#pragma unroll
        for (int ni = 0; ni < 4; ni++) {
            int col = wc * 64 + ni * 16 + (lane & 15);
            atomicAdd(&csum[col], colS[ni]);
            atomicAdd(&csq[col],  colQ[ni]);
        }
        __syncthreads();
        if (tid < 128) {
            atomicAdd(&sums[tid],       csum[tid]);
            atomicAdd(&sums[128 + tid], csq[tid]);
        }
    }
}

// ---------------- fused edge kernel (round-9 champion structure, verbatim) ----------------
__global__ __launch_bounds__(512, 8) void edge_mfma(const float* __restrict__ e,
                                                    const int* __restrict__ src,
                                                    const int* __restrict__ dst,
                                                    const ushort_t* __restrict__ Qm,
                                                    const ushort_t* __restrict__ Km,
                                                    const ushort_t* __restrict__ WeF,
                                                    const int* __restrict__ rank,
                                                    float* __restrict__ S,
                                                    float* __restrict__ out_e) {
    __shared__ __align__(16) unsigned char Asm[16384];
    __shared__ float sm[64][8];
    const int tid  = threadIdx.x;
    const int lane = tid & 63;
    const int wid  = tid >> 6;
    const int wr   = wid >> 2;
    const int wc   = wid & 3;
    const int e0   = blockIdx.x * 64;

    {   // stage e tile (f32 -> bf16 LDS) + f32 pass-through copy
        int row = tid >> 3;
        int c0  = (tid & 7) * 16;
        const float* ep = &e[(size_t)(e0 + row) * 128 + c0];
        float*       op = &out_e[(size_t)(e0 + row) * 128 + c0];
        float4 v4[4];
#pragma unroll
        for (int j = 0; j < 4; j++) v4[j] = ldg4(ep + 4 * j);
#pragma unroll
        for (int j = 0; j < 4; j++) *(float4*)(op + 4 * j) = v4[j];
        int chunk = c0 >> 6;
        int klb   = (c0 & 63) * 2;
        int s     = (row & 7) << 4;
        uint4 w0, w1;
        w0.x = pk(v4[0].x, v4[0].y); w0.y = pk(v4[0].z, v4[0].w);
        w0.z = pk(v4[1].x, v4[1].y); w0.w = pk(v4[1].z, v4[1].w);
        w1.x = pk(v4[2].x, v4[2].y); w1.y = pk(v4[2].z, v4[2].w);
        w1.z = pk(v4[3].x, v4[3].y); w1.w = pk(v4[3].z, v4[3].w);
        *(uint4*)(Asm + chunk * 8192 + ((row * 128 + klb) ^ s))      = w0;
        *(uint4*)(Asm + chunk * 8192 + ((row * 128 + klb + 16) ^ s)) = w1;
    }
    __syncthreads();

    f32x4 acc[2][2];
#pragma unroll
    for (int i = 0; i < 2; i++)
#pragma unroll
        for (int j = 0; j < 2; j++) acc[i][j] = (f32x4){0.f, 0.f, 0.f, 0.f};

#pragma unroll
    for (int k0 = 0; k0 < 128; k0 += 32) {
        int chunk = k0 >> 6;
        int klb   = (k0 & 63) * 2;
        int kc    = k0 >> 5;
        short8 a[2];
#pragma unroll
        for (int mi = 0; mi < 2; mi++) {
            int arow = wr * 32 + mi * 16 + (lane & 15);
            int byte = chunk * 8192 + ((arow * 128 + klb + (lane >> 4) * 16) ^ ((arow & 7) << 4));
            a[mi] = *(const short8*)(Asm + byte);
        }
#pragma unroll
        for (int ni = 0; ni < 2; ni++) {
            int cg = wc * 2 + ni;
            short8 b = *(const short8*)(WeF + ((size_t)((cg * 4 + kc) * 64 + lane)) * 8);
#pragma unroll
            for (int mi = 0; mi < 2; mi++)
                acc[mi][ni] = __builtin_amdgcn_mfma_f32_16x16x32_bf16(a[mi], b, acc[mi][ni], 0, 0, 0);
        }
    }

    // epilogue: gather bf16 K[src]*Q[dst], 16-lane reduce, exp -> LDS
#pragma unroll
    for (int mi = 0; mi < 2; mi++) {
        int rows[4], sidx[4], didx[4];
#pragma unroll
        for (int r = 0; r < 4; r++) {
            rows[r] = e0 + wr * 32 + mi * 16 + ((lane >> 4) << 2) + r;
            sidx[r] = src[rows[r]];
            didx[r] = dst[rows[r]];
        }
#pragma unroll
        for (int ni = 0; ni < 2; ni++) {
            int head = wc * 2 + ni;
            int col  = head * 16 + (lane & 15);
            float pv[4];
#pragma unroll
            for (int r = 0; r < 4; r++) {
                float kv = bf2f(Km[(size_t)sidx[r] * 128 + col]);
                float qv = bf2f(Qm[(size_t)didx[r] * 128 + col]);
                pv[r] = acc[mi][ni][r] * kv * qv;
            }
#pragma unroll
            for (int off = 1; off < 16; off <<= 1)
#pragma unroll
                for (int r = 0; r < 4; r++) pv[r] += __shfl_xor(pv[r], off, 64);
            if ((lane & 15) == 0) {
#pragma unroll
                for (int r = 0; r < 4; r++) {
                    float v = fminf(fmaxf(0.25f * pv[r], -5.f), 5.f);
                    sm[rows[r] - e0][head] = __expf(v);
                }
            }
        }
    }
    __syncthreads();
    if (tid < 64) {
        int rk = rank[e0 + tid];
        float4 a0 = *(const float4*)&sm[tid][0];
        float4 a1 = *(const float4*)&sm[tid][4];
        *(float4*)&S[(size_t)rk * 8]     = a0;
        *(float4*)&S[(size_t)rk * 8 + 4] = a1;
    }
}

// ---------------- aggregation: wave-per-node (8 nodes/block), f32 S + bf16 V, bf16 out ----------------
__global__ __launch_bounds__(512) void agg_kernel(const uint_t* __restrict__ Vu,
                                                  const float* __restrict__ S,
                                                  const int* __restrict__ start,
                                                  const int* __restrict__ srcs,
                                                  uint_t* __restrict__ HAu) {
    const int lane = threadIdx.x & 63;
    const int n = blockIdx.x * 8 + (threadIdx.x >> 6);
    if (n >= N_NODES) return;
    const int s0 = start[n];
    const int s1 = start[n + 1];
    const int h  = lane >> 3;
    float a0 = 0.f, a1 = 0.f, z = 0.f;
    int i = s0;
    for (; i + 4 <= s1; i += 4) {
        int m0 = srcs[i], m1 = srcs[i + 1], m2 = srcs[i + 2], m3 = srcs[i + 3];
        float t0 = S[(size_t)i * 8 + h];
        float t1 = S[(size_t)(i + 1) * 8 + h];
        float t2 = S[(size_t)(i + 2) * 8 + h];
        float t3 = S[(size_t)(i + 3) * 8 + h];
        uint_t v0 = Vu[(size_t)m0 * 64 + lane];
        uint_t v1 = Vu[(size_t)m1 * 64 + lane];
        uint_t v2 = Vu[(size_t)m2 * 64 + lane];
        uint_t v3 = Vu[(size_t)m3 * 64 + lane];
        a0 = fmaf(t0, bf2f((ushort_t)v0), a0); a1 = fmaf(t0, bf2f((ushort_t)(v0 >> 16)), a1);
        a0 = fmaf(t1, bf2f((ushort_t)v1), a0); a1 = fmaf(t1, bf2f((ushort_t)(v1 >> 16)), a1);
        a0 = fmaf(t2, bf2f((ushort_t)v2), a0); a1 = fmaf(t2, bf2f((ushort_t)(v2 >> 16)), a1);
        a0 = fmaf(t3, bf2f((ushort_t)v3), a0); a1 = fmaf(t3, bf2f((ushort_t)(v3 >> 16)), a1);
        z += t0 + t1 + t2 + t3;
    }
    for (; i < s1; i++) {
        int m = srcs[i];
        float t = S[(size_t)i * 8 + h];
        uint_t v = Vu[(size_t)m * 64 + lane];
        a0 = fmaf(t, bf2f((ushort_t)v), a0);
        a1 = fmaf(t, bf2f((ushort_t)(v >> 16)), a1);
        z += t;
    }
    float inv = 1.f / (z + 1e-6f);
    HAu[(size_t)n * 64 + lane] = pk(a0 * inv, a1 * inv);
}

// ---------------- batch norm: finalize sums -> scale/shift; apply y = x*scale+shift ----------------
__global__ void bn_finalize(const float* __restrict__ sums,
                            const float* __restrict__ gamma,
                            const float* __restrict__ beta,
                            float* __restrict__ ss) {
    int c = threadIdx.x;   // 128
    float mu  = sums[c] * (1.f / (float)N_NODES);
    float var = sums[128 + c] * (1.f / (float)N_NODES) - mu * mu;
    float scale = rsqrtf(var + 1e-5f) * gamma[c];
    ss[c]       = scale;
    ss[128 + c] = beta[c] - mu * scale;
}

__global__ __launch_bounds__(256) void bn_apply_f32(const float* __restrict__ X,
                                                    const float* __restrict__ ss,
                                                    float* __restrict__ Y) {
    const size_t total = (size_t)N_NODES * 128;
    const size_t step = (size_t)gridDim.x * blockDim.x * 4;
    for (size_t i = ((size_t)blockIdx.x * blockDim.x + threadIdx.x) * 4; i < total; i += step) {
        float4 x = ldg4(&X[i]);
        int c = (int)(i & 127);
        float4 y;
        y.x = x.x * ss[c + 0] + ss[128 + c + 0];
        y.y = x.y * ss[c + 1] + ss[128 + c + 1];
        y.z = x.z * ss[c + 2] + ss[128 + c + 2];
        y.w = x.w * ss[c + 3] + ss[128 + c + 3];
        *(float4*)(&Y[i]) = y;
    }
}

extern "C" void kernel_launch(void* const* d_in, const int* in_sizes, int n_in,
                              void* d_out, int out_size, void* d_ws, size_t ws_size,
                              hipStream_t stream) {
    (void)in_sizes; (void)n_in; (void)out_size; (void)ws_size;
    const int*   src   = (const int*)d_in[0];
    const int*   dst   = (const int*)d_in[1];
    const float* h     = (const float*)d_in[2];
    const float* e     = (const float*)d_in[3];
    const float* Wq    = (const float*)d_in[5];
    const float* Wk    = (const float*)d_in[6];
    const float* Wv    = (const float*)d_in[7];
    const float* We    = (const float*)d_in[8];
    const float* Wsdp  = (const float*)d_in[9];
    const float* bsdp  = (const float*)d_in[10];
    const float* Wh1   = (const float*)d_in[11];
    const float* bh1   = (const float*)d_in[12];
    const float* Wh2   = (const float*)d_in[13];
    const float* bh2   = (const float*)d_in[14];
    const float* gamma = (const float*)d_in[15];
    const float* beta  = (const float*)d_in[16];
    float* out = (float*)d_out;

    float* ws = (float*)d_ws;
    const size_t NM = (size_t)N_NODES * 128;   // 6.4M elements
    ushort_t* Q16  = (ushort_t*)ws;
    ushort_t* K16  = Q16 + NM;
    ushort_t* V16  = Q16 + 2 * NM;
    ushort_t* HA16 = (ushort_t*)(ws + 3 * NM / 2);
    float*    Kb   = ws + 2 * NM;
    float*    Sb   = ws + 3 * NM;   // f32 scores, sorted, [pos][8]
    float*    T1r  = ws + 4 * NM;
    ushort_t* T16  = (ushort_t*)T1r;
    float*    STATS = ws + 6 * NM;
    int* hist   = (int*)(STATS + 1024);
    int* startp = hist + N_NODES;
    int* cursor = startp + N_NODES + 1;
    ushort_t* prep = (ushort_t*)(((uintptr_t)(cursor + N_NODES) + 255) & ~(uintptr_t)255);
    ushort_t* WeF  = prep + (size_t)18 * 8192;

    int* rank = (int*)T1r;
    int* srcs = rank + E_EDGES;

    float* sums1 = STATS;
    float* ss1   = STATS + 256;
    float* sums2 = STATS + 512;
    float* ss2   = STATS + 768;

    prep_weights<<<18, 256, 0, stream>>>(Wq, Wk, Wv, We, Wsdp, Wh1, Wh2, prep);
    prep_we_frag<<<8, 256, 0, stream>>>(We, WeF);

    hipMemsetAsync(STATS, 0, (1024 + N_NODES) * sizeof(float), stream);

    hist_kernel<<<(E_EDGES + 255) / 256, 256, 0, stream>>>(dst, hist);
    scan_kernel<<<1, 1024, 0, stream>>>(hist, startp, cursor);
    scatter_kernel<<<(E_EDGES + 255) / 256, 256, 0, stream>>>(src, dst, cursor, rank, srcs);

    const int rt128 = (N_NODES + 127) / 128;   // 391
    const int rt64  = (N_NODES + 63) / 64;     // 782

    // q,k,v fused (bf16 out): h staged once, 3 matrices
    qkv_fused<<<rt64, 256, 0, stream>>>(h, prep, Q16, N_NODES);

    // fused edge scores (sorted f32 S, [pos][8]) + e pass-through copy — round-9 champion
    edge_mfma<<<E_EDGES / 64, 512, 0, stream>>>(e, src, dst, Q16, K16, WeF,
                                                rank, Sb, out + NM);

    // aggregation -> h_attn bf16 (8 nodes/block)
    agg_kernel<<<(N_NODES + 7) / 8, 512, 0, stream>>>((const uint_t*)V16, Sb, startp, srcs,
                                                      (uint_t*)HA16);

    // sdp projection + residual h -> Kb (pre-BN1), fused BN1 stats
    gemm_bf16<64, 0, 1, 0, 1, 0><<<dim3(rt64, 1), 256, 0, stream>>>(
        HA16, N_NODES, 128, prep + (size_t)8 * 8192, 2, bsdp, h, Kb, 128, 0, 0, sums1, nullptr);

    bn_finalize<<<1, 128, 0, stream>>>(sums1, gamma, beta, ss1);

    // FFN1: T16 = relu(bn1(Kb) @ Wh1 + bh1), bf16 out — BN1 applied during A-staging
    gemm_bf16<128, 1, 0, 0, 0, 1><<<dim3(rt128, 2), 256, 0, stream>>>(
        Kb, N_NODES, 128, prep + (size_t)10 * 8192, 2, bh1, nullptr, T16, 256, 128, 1, nullptr, ss1);
    // FFN2: Kb = T16 @ Wh2 + bh2 + bn1(Kb) resid (f32 + ss), fused BN2 stats
    gemm_bf16<64, 0, 1, 2, 1, 0><<<dim3(rt64, 1), 256, 0, stream>>>(
        T16, N_NODES, 256, prep + (size_t)14 * 8192, 4, bh2, Kb, Kb, 128, 0, 0, sums2, ss1);

    bn_finalize<<<1, 128, 0, stream>>>(sums2, gamma, beta, ss2);
    bn_apply_f32<<<2048, 256, 0, stream>>>(Kb, ss2, out);
}